// Round 3
// baseline (20327.126 us; speedup 1.0000x reference)
//
#include <hip/hip_runtime.h>

#define S_  5184
#define C_  768
#define NH_ 12
#define HD_ 64
#define FF_ 3072
#define WW_ 72

__device__ __forceinline__ float bf2f(unsigned short u){
    unsigned int i = ((unsigned int)u) << 16; float f; __builtin_memcpy(&f,&i,4); return f;
}
__device__ __forceinline__ unsigned short f2bf(float f){
    unsigned int i; __builtin_memcpy(&i,&f,4);
    unsigned int r = (i + 0x7fffu + ((i>>16)&1u)) >> 16;
    return (unsigned short)r;
}
__device__ __forceinline__ float ldf(float v){ return v; }
__device__ __forceinline__ float ldf(unsigned short v){ return bf2f(v); }

// ---------------- LayerNorm: (bf16|f32) in -> bf16 out ----------------
template<typename TIN>
__global__ __launch_bounds__(256) void ln_k(const TIN* __restrict__ x,
                                            const float* __restrict__ g,
                                            const float* __restrict__ b,
                                            unsigned short* __restrict__ out)
{
    int row = blockIdx.x, tid = threadIdx.x;
    const TIN* xr = x + (size_t)row * C_;
    float v0 = ldf(xr[tid]), v1 = ldf(xr[tid+256]), v2 = ldf(xr[tid+512]);
    float s = v0+v1+v2, q = v0*v0+v1*v1+v2*v2;
    #pragma unroll
    for (int off=32; off; off>>=1){ s += __shfl_xor(s,off); q += __shfl_xor(q,off); }
    __shared__ float ss[4], qq[4], mshare[2];
    int lane = tid & 63, wv = tid >> 6;
    if (!lane){ ss[wv] = s; qq[wv] = q; }
    __syncthreads();
    if (!tid){
        float S2 = ss[0]+ss[1]+ss[2]+ss[3];
        float Q2 = qq[0]+qq[1]+qq[2]+qq[3];
        float mean = S2 * (1.f/C_);
        float var  = Q2 * (1.f/C_) - mean*mean;
        mshare[0] = mean; mshare[1] = rsqrtf(var + 1e-6f);
    }
    __syncthreads();
    float mean = mshare[0], inv = mshare[1];
    unsigned short* orow = out + (size_t)row * C_;
    orow[tid]     = f2bf((v0-mean)*inv*g[tid]     + b[tid]);
    orow[tid+256] = f2bf((v1-mean)*inv*g[tid+256] + b[tid+256]);
    orow[tid+512] = f2bf((v2-mean)*inv*g[tid+512] + b[tid+512]);
}

// ---------------- RoPE tables: cos/sin (S,64) f32 ----------------
__global__ __launch_bounds__(256) void rope_tables_k(float* __restrict__ cosT,
                                                     float* __restrict__ sinT)
{
    int idx = blockIdx.x * 256 + threadIdx.x;     // over S*32 pairs
    if (idx >= S_*32) return;
    int s = idx >> 5, i = idx & 31;
    int hh = s / WW_, ww = s % WW_;
    int m = i & 15;
    float coord = (i < 16) ? (float)hh : (float)ww;
    float freq = powf(10000.0f, -(float)m / 16.0f);
    float a = coord * freq;
    float c = cosf(a), sn = sinf(a);
    cosT[s*64 + 2*i]   = c;  cosT[s*64 + 2*i+1] = c;
    sinT[s*64 + 2*i]   = sn; sinT[s*64 + 2*i+1] = sn;
}

// ---------------- RoPE apply (in-place on bf16 q,k) ----------------
__global__ __launch_bounds__(256) void rope_apply_k(unsigned short* __restrict__ q,
                                                    unsigned short* __restrict__ k,
                                                    const float* __restrict__ cosT,
                                                    const float* __restrict__ sinT)
{
    int idx = blockIdx.x * 256 + threadIdx.x;     // over S * NH * 32 pairs
    if (idx >= S_*NH_*32) return;
    int s = idx / (NH_*32);
    int p = idx % (NH_*32);
    int h = p >> 5, i = p & 31;
    size_t base = (size_t)s*C_ + h*HD_ + 2*i;
    float c = cosT[s*64 + 2*i], sn = sinT[s*64 + 2*i];
    float x0 = bf2f(q[base]), x1 = bf2f(q[base+1]);
    q[base]   = f2bf(x0*c - x1*sn);
    q[base+1] = f2bf(x1*c + x0*sn);
    x0 = bf2f(k[base]); x1 = bf2f(k[base+1]);
    k[base]   = f2bf(x0*c - x1*sn);
    k[base+1] = f2bf(x1*c + x0*sn);
}

// ---------------- Generic GEMM: bf16 A (M,K) @ f32 W (K,N) + bias ----------------
// EPI 0: out bf16 = acc+bias
// EPI 1: out bf16 = gelu(acc+bias)
// EPI 2: out f32  = (acc+bias)*scale + addend (f32)
// EPI 3: out f32  = (acc+bias)*scale + addend (f32)
template<int EPI>
__global__ __launch_bounds__(256) void gemm_k(const unsigned short* __restrict__ A,
                                              const float* __restrict__ W,
                                              const float* __restrict__ bias,
                                              const float* __restrict__ scale,
                                              const float* __restrict__ addend,
                                              void* __restrict__ outp,
                                              int M, int N, int K)
{
    __shared__ float As[64][17];
    __shared__ float Bs[16][65];
    int t  = threadIdx.x;
    int tx = t & 15, ty = t >> 4;
    int bm = blockIdx.y * 64, bn = blockIdx.x * 64;
    float acc[4][4] = {};
    for (int k0 = 0; k0 < K; k0 += 16) {
        #pragma unroll
        for (int r = 0; r < 4; r++) {
            int idx = t + r*256;            // 0..1023
            int m = idx >> 4, kk = idx & 15;
            As[m][kk] = bf2f(A[(size_t)(bm+m)*K + k0 + kk]);
        }
        #pragma unroll
        for (int r = 0; r < 4; r++) {
            int idx = t + r*256;
            int kk = idx >> 6, n = idx & 63;
            Bs[kk][n] = W[(size_t)(k0+kk)*N + bn + n];
        }
        __syncthreads();
        #pragma unroll
        for (int kk = 0; kk < 16; kk++) {
            float a[4], bb[4];
            #pragma unroll
            for (int i = 0; i < 4; i++) a[i]  = As[ty*4+i][kk];
            #pragma unroll
            for (int j = 0; j < 4; j++) bb[j] = Bs[kk][tx*4+j];
            #pragma unroll
            for (int i = 0; i < 4; i++)
                #pragma unroll
                for (int j = 0; j < 4; j++)
                    acc[i][j] = fmaf(a[i], bb[j], acc[i][j]);
        }
        __syncthreads();
    }
    #pragma unroll
    for (int i = 0; i < 4; i++) {
        int m = bm + ty*4 + i;
        #pragma unroll
        for (int j = 0; j < 4; j++) {
            int n = bn + tx*4 + j;
            float v = acc[i][j] + bias[n];
            if (EPI == 1) v = 0.5f * v * (1.f + erff(v * 0.70710678f));
            size_t o = (size_t)m * N + n;
            if (EPI == 2)
                ((float*)outp)[o] = v*scale[n] + addend[o];
            else if (EPI == 3)
                ((float*)outp)[o] = v*scale[n] + addend[o];
            else
                ((unsigned short*)outp)[o] = f2bf(v);
        }
    }
}

// ---------------- Attention: one (head, q-row) per block ----------------
__global__ __launch_bounds__(256) void attn_k(const unsigned short* __restrict__ Q,
                                              const unsigned short* __restrict__ Kb,
                                              const unsigned short* __restrict__ V,
                                              unsigned short* __restrict__ O)
{
    int qi = blockIdx.x, h = blockIdx.y, tid = threadIdx.x;
    __shared__ float qs[64];
    if (tid < 64) qs[tid] = bf2f(Q[(size_t)qi*C_ + h*HD_ + tid]) * 0.125f;
    __syncthreads();

    float o[64];
    #pragma unroll
    for (int d = 0; d < 64; d++) o[d] = 0.f;
    float m = -INFINITY, l = 0.f;

    for (int j = tid; j < S_; j += 256) {
        size_t kb = (size_t)j*C_ + h*HD_;
        const ushort4* kr = (const ushort4*)(Kb + kb);
        float s = 0.f;
        #pragma unroll
        for (int u = 0; u < 16; u++) {
            ushort4 p = kr[u];
            s = fmaf(qs[4*u+0], bf2f(p.x), s);
            s = fmaf(qs[4*u+1], bf2f(p.y), s);
            s = fmaf(qs[4*u+2], bf2f(p.z), s);
            s = fmaf(qs[4*u+3], bf2f(p.w), s);
        }
        const ushort4* vr = (const ushort4*)(V + kb);
        if (s <= m) {
            float p = __expf(s - m);
            l += p;
            #pragma unroll
            for (int u = 0; u < 16; u++) {
                ushort4 pv = vr[u];
                o[4*u+0] = fmaf(p, bf2f(pv.x), o[4*u+0]);
                o[4*u+1] = fmaf(p, bf2f(pv.y), o[4*u+1]);
                o[4*u+2] = fmaf(p, bf2f(pv.z), o[4*u+2]);
                o[4*u+3] = fmaf(p, bf2f(pv.w), o[4*u+3]);
            }
        } else {
            float corr = __expf(m - s);
            m = s;
            l = l*corr + 1.f;
            #pragma unroll
            for (int u = 0; u < 16; u++) {
                ushort4 pv = vr[u];
                o[4*u+0] = fmaf(o[4*u+0], corr, bf2f(pv.x));
                o[4*u+1] = fmaf(o[4*u+1], corr, bf2f(pv.y));
                o[4*u+2] = fmaf(o[4*u+2], corr, bf2f(pv.z));
                o[4*u+3] = fmaf(o[4*u+3], corr, bf2f(pv.w));
            }
        }
    }

    // block combine
    __shared__ float red[256];
    red[tid] = m; __syncthreads();
    for (int s2 = 128; s2 > 0; s2 >>= 1) {
        if (tid < s2) red[tid] = fmaxf(red[tid], red[tid+s2]);
        __syncthreads();
    }
    float M = red[0]; __syncthreads();
    float corr = __expf(m - M);
    red[tid] = l * corr; __syncthreads();
    for (int s2 = 128; s2 > 0; s2 >>= 1) {
        if (tid < s2) red[tid] += red[tid+s2];
        __syncthreads();
    }
    float L = red[0];

    __shared__ float osum[4][64];
    int lane = tid & 63, wv = tid >> 6;
    #pragma unroll
    for (int d = 0; d < 64; d++) {
        float v = o[d] * corr;
        v += __shfl_xor(v, 32); v += __shfl_xor(v, 16); v += __shfl_xor(v, 8);
        v += __shfl_xor(v, 4);  v += __shfl_xor(v, 2);  v += __shfl_xor(v, 1);
        if (!lane) osum[wv][d] = v;
    }
    __syncthreads();
    if (tid < 64) {
        float v = osum[0][tid] + osum[1][tid] + osum[2][tid] + osum[3][tid];
        O[(size_t)qi*C_ + h*HD_ + tid] = f2bf(v / L);
    }
}

extern "C" void kernel_launch(void* const* d_in, const int* in_sizes, int n_in,
                              void* d_out, int out_size, void* d_ws, size_t ws_size,
                              hipStream_t stream)
{
    const float* hidden = (const float*)d_in[0];
    const float* wq  = (const float*)d_in[1];
    const float* bq  = (const float*)d_in[2];
    const float* wk  = (const float*)d_in[3];
    const float* bk  = (const float*)d_in[4];
    const float* wv  = (const float*)d_in[5];
    const float* bv  = (const float*)d_in[6];
    const float* wo  = (const float*)d_in[7];
    const float* bo  = (const float*)d_in[8];
    const float* g1  = (const float*)d_in[9];
    const float* b1  = (const float*)d_in[10];
    const float* g2  = (const float*)d_in[11];
    const float* b2  = (const float*)d_in[12];
    const float* wf1 = (const float*)d_in[13];
    const float* bf1 = (const float*)d_in[14];
    const float* wf2 = (const float*)d_in[15];
    const float* bf2_ = (const float*)d_in[16];
    const float* ls1 = (const float*)d_in[17];
    const float* ls2 = (const float*)d_in[18];

    char* ws = (char*)d_ws;
    size_t off = 0;
    auto alloc = [&](size_t bytes) { char* p = ws + off; off += (bytes + 255) & ~(size_t)255; return p; };

    float* res1          = (float*)alloc((size_t)S_*C_*4);
    float* cosT          = (float*)alloc((size_t)S_*64*4);
    float* sinT          = (float*)alloc((size_t)S_*64*4);
    unsigned short* lnb  = (unsigned short*)alloc((size_t)S_*C_*2);
    unsigned short* qb   = (unsigned short*)alloc((size_t)S_*C_*2);
    unsigned short* kb   = (unsigned short*)alloc((size_t)S_*C_*2);
    unsigned short* vb   = (unsigned short*)alloc((size_t)S_*C_*2);
    unsigned short* ob   = (unsigned short*)alloc((size_t)S_*C_*2);
    unsigned short* fc1b = qb;   // alias: q/k/v/o region (4*S*C*2 == S*FF*2), dead by then
    float* outb = (float*)d_out;

    // 1. LN1
    hipLaunchKernelGGL(ln_k<float>, dim3(S_), dim3(256), 0, stream, hidden, g1, b1, lnb);
    // 2. RoPE tables
    hipLaunchKernelGGL(rope_tables_k, dim3((S_*32 + 255)/256), dim3(256), 0, stream, cosT, sinT);
    // 3. QKV projections
    hipLaunchKernelGGL(gemm_k<0>, dim3(C_/64, S_/64), dim3(256), 0, stream,
                       lnb, wq, bq, (const float*)nullptr, (const float*)nullptr, (void*)qb, S_, C_, C_);
    hipLaunchKernelGGL(gemm_k<0>, dim3(C_/64, S_/64), dim3(256), 0, stream,
                       lnb, wk, bk, (const float*)nullptr, (const float*)nullptr, (void*)kb, S_, C_, C_);
    hipLaunchKernelGGL(gemm_k<0>, dim3(C_/64, S_/64), dim3(256), 0, stream,
                       lnb, wv, bv, (const float*)nullptr, (const float*)nullptr, (void*)vb, S_, C_, C_);
    // 4. RoPE on q,k
    hipLaunchKernelGGL(rope_apply_k, dim3((S_*NH_*32 + 255)/256), dim3(256), 0, stream,
                       qb, kb, cosT, sinT);
    // 5. attention
    hipLaunchKernelGGL(attn_k, dim3(S_, NH_), dim3(256), 0, stream, qb, kb, vb, ob);
    // 6. o-proj + ls1 + residual(f32 hidden) -> res1 (f32)
    hipLaunchKernelGGL(gemm_k<2>, dim3(C_/64, S_/64), dim3(256), 0, stream,
                       ob, wo, bo, ls1, hidden, (void*)res1, S_, C_, C_);
    // 7. LN2
    hipLaunchKernelGGL(ln_k<float>, dim3(S_), dim3(256), 0, stream, res1, g2, b2, lnb);
    // 8. fc1 + gelu
    hipLaunchKernelGGL(gemm_k<1>, dim3(FF_/64, S_/64), dim3(256), 0, stream,
                       lnb, wf1, bf1, (const float*)nullptr, (const float*)nullptr, (void*)fc1b, S_, FF_, C_);
    // 9. fc2 + ls2 + residual(f32 res1) -> d_out (f32)
    hipLaunchKernelGGL(gemm_k<3>, dim3(C_/64, S_/64), dim3(256), 0, stream,
                       fc1b, wf2, bf2_, ls2, res1, (void*)outb, S_, C_, FF_);
    (void)in_sizes; (void)n_in; (void)out_size; (void)ws_size;
}

// Round 4
// 669.582 us; speedup vs baseline: 30.3579x; 30.3579x over previous
//
#include <hip/hip_runtime.h>

#define S_  5184
#define C_  768
#define NH_ 12
#define HD_ 64
#define FF_ 3072
#define WW_ 72

typedef __attribute__((ext_vector_type(8))) short bf16x8;
typedef __attribute__((ext_vector_type(4))) float f32x4;

__device__ __forceinline__ float bf2f(unsigned short u){
    unsigned int i = ((unsigned int)u) << 16; float f; __builtin_memcpy(&f,&i,4); return f;
}
__device__ __forceinline__ unsigned short f2bf(float f){
    unsigned int i; __builtin_memcpy(&i,&f,4);
    unsigned int r = (i + 0x7fffu + ((i>>16)&1u)) >> 16;
    return (unsigned short)r;
}
__device__ __forceinline__ float ldf(float v){ return v; }
__device__ __forceinline__ float ldf(unsigned short v){ return bf2f(v); }

__device__ __forceinline__ void gload16(const void* g, const void* l) {
    __builtin_amdgcn_global_load_lds((const __attribute__((address_space(1))) void*)g,
                                     (__attribute__((address_space(3))) void*)l, 16, 0, 0);
}

// ---------------- LayerNorm: (f32) in -> bf16 out ----------------
template<typename TIN>
__global__ __launch_bounds__(256) void ln_k(const TIN* __restrict__ x,
                                            const float* __restrict__ g,
                                            const float* __restrict__ b,
                                            unsigned short* __restrict__ out)
{
    int row = blockIdx.x, tid = threadIdx.x;
    const TIN* xr = x + (size_t)row * C_;
    float v0 = ldf(xr[tid]), v1 = ldf(xr[tid+256]), v2 = ldf(xr[tid+512]);
    float s = v0+v1+v2, q = v0*v0+v1*v1+v2*v2;
    #pragma unroll
    for (int off=32; off; off>>=1){ s += __shfl_xor(s,off); q += __shfl_xor(q,off); }
    __shared__ float ss[4], qq[4], mshare[2];
    int lane = tid & 63, wv = tid >> 6;
    if (!lane){ ss[wv] = s; qq[wv] = q; }
    __syncthreads();
    if (!tid){
        float S2 = ss[0]+ss[1]+ss[2]+ss[3];
        float Q2 = qq[0]+qq[1]+qq[2]+qq[3];
        float mean = S2 * (1.f/C_);
        float var  = Q2 * (1.f/C_) - mean*mean;
        mshare[0] = mean; mshare[1] = rsqrtf(var + 1e-6f);
    }
    __syncthreads();
    float mean = mshare[0], inv = mshare[1];
    unsigned short* orow = out + (size_t)row * C_;
    orow[tid]     = f2bf((v0-mean)*inv*g[tid]     + b[tid]);
    orow[tid+256] = f2bf((v1-mean)*inv*g[tid+256] + b[tid+256]);
    orow[tid+512] = f2bf((v2-mean)*inv*g[tid+512] + b[tid+512]);
}

// ---------------- RoPE tables ----------------
__global__ __launch_bounds__(256) void rope_tables_k(float* __restrict__ cosT,
                                                     float* __restrict__ sinT)
{
    int idx = blockIdx.x * 256 + threadIdx.x;
    if (idx >= S_*32) return;
    int s = idx >> 5, i = idx & 31;
    int hh = s / WW_, ww = s % WW_;
    int m = i & 15;
    float coord = (i < 16) ? (float)hh : (float)ww;
    float freq = powf(10000.0f, -(float)m / 16.0f);
    float a = coord * freq;
    float c = cosf(a), sn = sinf(a);
    cosT[s*64 + 2*i]   = c;  cosT[s*64 + 2*i+1] = c;
    sinT[s*64 + 2*i]   = sn; sinT[s*64 + 2*i+1] = sn;
}

// ---------------- RoPE apply (q scaled by 0.125) ----------------
__global__ __launch_bounds__(256) void rope_apply_k(unsigned short* __restrict__ q,
                                                    unsigned short* __restrict__ k,
                                                    const float* __restrict__ cosT,
                                                    const float* __restrict__ sinT)
{
    int idx = blockIdx.x * 256 + threadIdx.x;
    if (idx >= S_*NH_*32) return;
    int s = idx / (NH_*32);
    int p = idx % (NH_*32);
    int h = p >> 5, i = p & 31;
    size_t base = (size_t)s*C_ + h*HD_ + 2*i;
    float c = cosT[s*64 + 2*i], sn = sinT[s*64 + 2*i];
    float x0 = bf2f(q[base]), x1 = bf2f(q[base+1]);
    q[base]   = f2bf((x0*c - x1*sn) * 0.125f);
    q[base+1] = f2bf((x1*c + x0*sn) * 0.125f);
    x0 = bf2f(k[base]); x1 = bf2f(k[base+1]);
    k[base]   = f2bf(x0*c - x1*sn);
    k[base+1] = f2bf(x1*c + x0*sn);
}

// ---------------- Weight transpose: f32 W(K,N) -> bf16 WT(N,K) ----------------
__global__ __launch_bounds__(256) void transpose_w(const float* __restrict__ W,
                                                   unsigned short* __restrict__ WT,
                                                   int K, int N)
{
    __shared__ float t[32][33];
    int tx = threadIdx.x, ty = threadIdx.y;
    int n0 = blockIdx.x * 32, k0 = blockIdx.y * 32;
    #pragma unroll
    for (int i = 0; i < 4; i++)
        t[ty + i*8][tx] = W[(size_t)(k0 + ty + i*8)*N + n0 + tx];
    __syncthreads();
    #pragma unroll
    for (int i = 0; i < 4; i++)
        WT[(size_t)(n0 + ty + i*8)*K + k0 + tx] = f2bf(t[tx][ty + i*8]);
}

// ---------------- MFMA GEMM: bf16 A(M,K) @ bf16 BT(N,K)^T + bias ----------------
// EPI 0: bf16 out = acc+bias          (packed M,N)
// EPI 1: bf16 out = gelu(acc+bias)
// EPI 2: f32  out = (acc+bias)*scale + addend
// EPI 3: bf16 out = acc+bias, TRANSPOSED to out[n*S_ + m]  (V_t)
template<int EPI>
__global__ __launch_bounds__(256) void gemm_mfma(const unsigned short* __restrict__ A,
                                                 const unsigned short* __restrict__ BT,
                                                 const float* __restrict__ bias,
                                                 const float* __restrict__ scale,
                                                 const float* __restrict__ addend,
                                                 void* __restrict__ outp,
                                                 int M, int N, int K)
{
    __shared__ __align__(16) unsigned short As[8][128][8];   // [kg][row][j] 16KB
    __shared__ __align__(16) unsigned short Bs[8][128][8];
    int tid = threadIdx.x;
    int w = tid >> 6, lane = tid & 63, lq = lane & 15, lk = lane >> 4;
    int wr = w >> 1, wc = w & 1;
    int bm = blockIdx.y * 128, bn = blockIdx.x * 128;

    f32x4 acc[4][4];
    #pragma unroll
    for (int i = 0; i < 4; i++)
        #pragma unroll
        for (int j = 0; j < 4; j++) acc[i][j] = 0;

    for (int kt = 0; kt < K; kt += 64) {
        #pragma unroll
        for (int u = 0; u < 4; u++) {
            int t = w*4 + u;
            int c = t*64 + lane;
            int kg = c >> 7, row = c & 127;
            int ra = bm + row; if (ra >= M) ra = M - 1;
            gload16(A + (size_t)ra*K + kt + kg*8, ((const unsigned short*)As) + t*512);
            gload16(BT + (size_t)(bn + row)*K + kt + kg*8, ((const unsigned short*)Bs) + t*512);
        }
        __syncthreads();
        #pragma unroll
        for (int kk = 0; kk < 2; kk++) {
            bf16x8 af[4], bfr[4];
            #pragma unroll
            for (int mi = 0; mi < 4; mi++)
                af[mi] = *(const bf16x8*)&As[kk*4 + lk][wr*64 + mi*16 + lq][0];
            #pragma unroll
            for (int ni = 0; ni < 4; ni++)
                bfr[ni] = *(const bf16x8*)&Bs[kk*4 + lk][wc*64 + ni*16 + lq][0];
            #pragma unroll
            for (int mi = 0; mi < 4; mi++)
                #pragma unroll
                for (int ni = 0; ni < 4; ni++)
                    acc[mi][ni] = __builtin_amdgcn_mfma_f32_16x16x32_bf16(af[mi], bfr[ni], acc[mi][ni], 0, 0, 0);
        }
        __syncthreads();
    }

    #pragma unroll
    for (int mi = 0; mi < 4; mi++) {
        #pragma unroll
        for (int ni = 0; ni < 4; ni++) {
            #pragma unroll
            for (int r = 0; r < 4; r++) {
                int m = bm + wr*64 + mi*16 + lk*4 + r;
                int n = bn + wc*64 + ni*16 + lq;
                if (m < M) {
                    float v = acc[mi][ni][r] + bias[n];
                    if (EPI == 0) {
                        ((unsigned short*)outp)[(size_t)m*N + n] = f2bf(v);
                    } else if (EPI == 1) {
                        v = 0.5f * v * (1.f + erff(v * 0.70710678f));
                        ((unsigned short*)outp)[(size_t)m*N + n] = f2bf(v);
                    } else if (EPI == 2) {
                        size_t o = (size_t)m*N + n;
                        ((float*)outp)[o] = v*scale[n] + addend[o];
                    } else {
                        ((unsigned short*)outp)[(size_t)n*S_ + m] = f2bf(v);
                    }
                }
            }
        }
    }
}

// ---------------- MFMA flash attention ----------------
// Q,K packed bf16 [s][C] (Q pre-scaled), Vt bf16 [C][S] (head-major d rows), O packed bf16 [s][C]
__global__ __launch_bounds__(256) void attn_mfma(const unsigned short* __restrict__ Q,
                                                 const unsigned short* __restrict__ Kb,
                                                 const unsigned short* __restrict__ Vt,
                                                 unsigned short* __restrict__ O)
{
    __shared__ __align__(16) unsigned short Ks[8][64][8];      // [dg][kv][j] 8KB
    __shared__ __align__(16) unsigned short Vs[8][64][8];      // [kvg][d][j] 8KB
    __shared__ __align__(16) unsigned short Ps[4][8][16][8];   // [wave][kvg][q][j] 8KB
    int tid = threadIdx.x;
    int w = tid >> 6, lane = tid & 63, lq = lane & 15, lk = lane >> 4;
    int qt = blockIdx.x, h = blockIdx.y;
    int q0 = qt * 64;

    // Q fragments (A operand): lane&15 = q-row, k = d
    bf16x8 qf[2];
    #pragma unroll
    for (int ks = 0; ks < 2; ks++)
        qf[ks] = *(const bf16x8*)(Q + (size_t)(q0 + w*16 + lq)*C_ + h*64 + ks*32 + lk*8);

    f32x4 oacc[4];
    #pragma unroll
    for (int df = 0; df < 4; df++) oacc[df] = 0;
    float m_[4] = {-INFINITY,-INFINITY,-INFINITY,-INFINITY};
    float l_[4] = {0.f,0.f,0.f,0.f};

    for (int t = 0; t < S_/64; t++) {
        int kv0 = t * 64;
        #pragma unroll
        for (int u = 0; u < 2; u++) {
            int tt = w*2 + u;
            gload16(Kb + (size_t)(kv0 + lane)*C_ + h*64 + tt*8,
                    ((const unsigned short*)Ks) + tt*512);
            gload16(Vt + (size_t)(h*64 + lane)*S_ + kv0 + tt*8,
                    ((const unsigned short*)Vs) + tt*512);
        }
        __syncthreads();

        // S = Q K^T  (per wave: 16q x 64kv)
        f32x4 s4[4];
        #pragma unroll
        for (int nf = 0; nf < 4; nf++) s4[nf] = 0;
        #pragma unroll
        for (int ks = 0; ks < 2; ks++) {
            #pragma unroll
            for (int nf = 0; nf < 4; nf++) {
                bf16x8 kf = *(const bf16x8*)&Ks[ks*4 + lk][nf*16 + lq][0];
                s4[nf] = __builtin_amdgcn_mfma_f32_16x16x32_bf16(qf[ks], kf, s4[nf], 0, 0, 0);
            }
        }

        // online softmax per q-row r (q = q0 + w*16 + lk*4 + r)
        #pragma unroll
        for (int r = 0; r < 4; r++) {
            float tm = fmaxf(fmaxf(s4[0][r], s4[1][r]), fmaxf(s4[2][r], s4[3][r]));
            tm = fmaxf(tm, __shfl_xor(tm, 1));
            tm = fmaxf(tm, __shfl_xor(tm, 2));
            tm = fmaxf(tm, __shfl_xor(tm, 4));
            tm = fmaxf(tm, __shfl_xor(tm, 8));
            float mn = fmaxf(m_[r], tm);
            float corr = __expf(m_[r] - mn);
            m_[r] = mn;
            float ps = 0.f;
            #pragma unroll
            for (int nf = 0; nf < 4; nf++) {
                float p = __expf(s4[nf][r] - mn);
                s4[nf][r] = p; ps += p;
            }
            ps += __shfl_xor(ps, 1);
            ps += __shfl_xor(ps, 2);
            ps += __shfl_xor(ps, 4);
            ps += __shfl_xor(ps, 8);
            l_[r] = l_[r]*corr + ps;
            #pragma unroll
            for (int df = 0; df < 4; df++) oacc[df][r] *= corr;
        }

        // P -> LDS (per-wave), layout [kvg][q][j]
        #pragma unroll
        for (int nf = 0; nf < 4; nf++) {
            #pragma unroll
            for (int r = 0; r < 4; r++) {
                int kv = nf*16 + lq;
                Ps[w][kv >> 3][lk*4 + r][kv & 7] = f2bf(s4[nf][r]);
            }
        }

        // O += P V   (A = P: lane&15=q, k=kv; B = V: lane&15=d, k=kv)
        #pragma unroll
        for (int ks = 0; ks < 2; ks++) {
            bf16x8 pa = *(const bf16x8*)&Ps[w][ks*4 + lk][lq][0];
            #pragma unroll
            for (int df = 0; df < 4; df++) {
                bf16x8 vf = *(const bf16x8*)&Vs[ks*4 + lk][df*16 + lq][0];
                oacc[df] = __builtin_amdgcn_mfma_f32_16x16x32_bf16(pa, vf, oacc[df], 0, 0, 0);
            }
        }
        __syncthreads();
    }

    #pragma unroll
    for (int df = 0; df < 4; df++) {
        #pragma unroll
        for (int r = 0; r < 4; r++) {
            int q = q0 + w*16 + lk*4 + r;
            int d = df*16 + lq;
            O[(size_t)q*C_ + h*64 + d] = f2bf(oacc[df][r] / l_[r]);
        }
    }
}

extern "C" void kernel_launch(void* const* d_in, const int* in_sizes, int n_in,
                              void* d_out, int out_size, void* d_ws, size_t ws_size,
                              hipStream_t stream)
{
    const float* hidden = (const float*)d_in[0];
    const float* wq  = (const float*)d_in[1];
    const float* bq  = (const float*)d_in[2];
    const float* wk  = (const float*)d_in[3];
    const float* bk  = (const float*)d_in[4];
    const float* wv  = (const float*)d_in[5];
    const float* bv  = (const float*)d_in[6];
    const float* wo  = (const float*)d_in[7];
    const float* bo  = (const float*)d_in[8];
    const float* g1  = (const float*)d_in[9];
    const float* b1  = (const float*)d_in[10];
    const float* g2  = (const float*)d_in[11];
    const float* b2  = (const float*)d_in[12];
    const float* wf1 = (const float*)d_in[13];
    const float* bf1 = (const float*)d_in[14];
    const float* wf2 = (const float*)d_in[15];
    const float* bf2_ = (const float*)d_in[16];
    const float* ls1 = (const float*)d_in[17];
    const float* ls2 = (const float*)d_in[18];

    char* ws = (char*)d_ws;
    size_t off = 0;
    auto alloc = [&](size_t bytes) { char* p = ws + off; off += (bytes + 255) & ~(size_t)255; return p; };

    float* res1          = (float*)alloc((size_t)S_*C_*4);
    float* cosT          = (float*)alloc((size_t)S_*64*4);
    float* sinT          = (float*)alloc((size_t)S_*64*4);
    unsigned short* lnb  = (unsigned short*)alloc((size_t)S_*C_*2);
    unsigned short* qb   = (unsigned short*)alloc((size_t)S_*C_*2);
    unsigned short* kb   = (unsigned short*)alloc((size_t)S_*C_*2);
    unsigned short* vtb  = (unsigned short*)alloc((size_t)S_*C_*2);   // V_t [C_][S_]
    unsigned short* ob   = (unsigned short*)alloc((size_t)S_*C_*2);
    unsigned short* fc1b = qb;   // alias qb..ob (4*S*C*2 == S*FF*2), dead by fc1
    unsigned short* wqT  = (unsigned short*)alloc((size_t)C_*C_*2);
    unsigned short* wkT  = (unsigned short*)alloc((size_t)C_*C_*2);
    unsigned short* wvT  = (unsigned short*)alloc((size_t)C_*C_*2);
    unsigned short* woT  = (unsigned short*)alloc((size_t)C_*C_*2);
    unsigned short* wf1T = (unsigned short*)alloc((size_t)C_*FF_*2);
    unsigned short* wf2T = (unsigned short*)alloc((size_t)C_*FF_*2);
    float* outb = (float*)d_out;

    // 0. weight transposes (f32 (K,N) -> bf16 (N,K))
    hipLaunchKernelGGL(transpose_w, dim3(C_/32, C_/32), dim3(32,8), 0, stream, wq,  wqT,  C_, C_);
    hipLaunchKernelGGL(transpose_w, dim3(C_/32, C_/32), dim3(32,8), 0, stream, wk,  wkT,  C_, C_);
    hipLaunchKernelGGL(transpose_w, dim3(C_/32, C_/32), dim3(32,8), 0, stream, wv,  wvT,  C_, C_);
    hipLaunchKernelGGL(transpose_w, dim3(C_/32, C_/32), dim3(32,8), 0, stream, wo,  woT,  C_, C_);
    hipLaunchKernelGGL(transpose_w, dim3(FF_/32, C_/32), dim3(32,8), 0, stream, wf1, wf1T, C_, FF_);
    hipLaunchKernelGGL(transpose_w, dim3(C_/32, FF_/32), dim3(32,8), 0, stream, wf2, wf2T, FF_, C_);
    // 1. LN1
    hipLaunchKernelGGL(ln_k<float>, dim3(S_), dim3(256), 0, stream, hidden, g1, b1, lnb);
    // 2. RoPE tables
    hipLaunchKernelGGL(rope_tables_k, dim3((S_*32 + 255)/256), dim3(256), 0, stream, cosT, sinT);
    // 3. QKV projections
    hipLaunchKernelGGL(gemm_mfma<0>, dim3(C_/128, 41), dim3(256), 0, stream,
                       lnb, wqT, bq, (const float*)nullptr, (const float*)nullptr, (void*)qb, S_, C_, C_);
    hipLaunchKernelGGL(gemm_mfma<0>, dim3(C_/128, 41), dim3(256), 0, stream,
                       lnb, wkT, bk, (const float*)nullptr, (const float*)nullptr, (void*)kb, S_, C_, C_);
    hipLaunchKernelGGL(gemm_mfma<3>, dim3(C_/128, 41), dim3(256), 0, stream,
                       lnb, wvT, bv, (const float*)nullptr, (const float*)nullptr, (void*)vtb, S_, C_, C_);
    // 4. RoPE on q,k (q scaled by 1/8)
    hipLaunchKernelGGL(rope_apply_k, dim3((S_*NH_*32 + 255)/256), dim3(256), 0, stream,
                       qb, kb, cosT, sinT);
    // 5. attention
    hipLaunchKernelGGL(attn_mfma, dim3(S_/64, NH_), dim3(256), 0, stream, qb, kb, vtb, ob);
    // 6. o-proj + ls1 + residual -> res1 (f32)
    hipLaunchKernelGGL(gemm_mfma<2>, dim3(C_/128, 41), dim3(256), 0, stream,
                       ob, woT, bo, ls1, hidden, (void*)res1, S_, C_, C_);
    // 7. LN2
    hipLaunchKernelGGL(ln_k<float>, dim3(S_), dim3(256), 0, stream, res1, g2, b2, lnb);
    // 8. fc1 + gelu
    hipLaunchKernelGGL(gemm_mfma<1>, dim3(FF_/128, 41), dim3(256), 0, stream,
                       lnb, wf1T, bf1, (const float*)nullptr, (const float*)nullptr, (void*)fc1b, S_, FF_, C_);
    // 9. fc2 + ls2 + residual -> d_out (f32)
    hipLaunchKernelGGL(gemm_mfma<2>, dim3(C_/128, 41), dim3(256), 0, stream,
                       fc1b, wf2T, bf2_, ls2, res1, (void*)outb, S_, C_, FF_);
    (void)in_sizes; (void)n_in; (void)out_size; (void)ws_size;
}

// Round 5
// 556.048 us; speedup vs baseline: 36.5565x; 1.2042x over previous
//
#include <hip/hip_runtime.h>

#define S_  5184
#define C_  768
#define NH_ 12
#define HD_ 64
#define FF_ 3072
#define WW_ 72

typedef __attribute__((ext_vector_type(8))) short bf16x8;
typedef __attribute__((ext_vector_type(4))) float f32x4;

__device__ __forceinline__ float bf2f(unsigned short u){
    unsigned int i = ((unsigned int)u) << 16; float f; __builtin_memcpy(&f,&i,4); return f;
}
__device__ __forceinline__ unsigned short f2bf(float f){
    unsigned int i; __builtin_memcpy(&i,&f,4);
    unsigned int r = (i + 0x7fffu + ((i>>16)&1u)) >> 16;
    return (unsigned short)r;
}
__device__ __forceinline__ float ldf(float v){ return v; }
__device__ __forceinline__ float ldf(unsigned short v){ return bf2f(v); }

__device__ __forceinline__ void gload16(const void* g, const void* l) {
    __builtin_amdgcn_global_load_lds((const __attribute__((address_space(1))) void*)g,
                                     (__attribute__((address_space(3))) void*)l, 16, 0, 0);
}
__device__ __forceinline__ unsigned int cvtpk(float lo, float hi){
    unsigned int r;
    asm volatile("v_cvt_pk_bf16_f32 %0, %1, %2" : "=v"(r) : "v"(lo), "v"(hi));
    return r;
}

// ---------------- LayerNorm ----------------
template<typename TIN>
__global__ __launch_bounds__(256) void ln_k(const TIN* __restrict__ x,
                                            const float* __restrict__ g,
                                            const float* __restrict__ b,
                                            unsigned short* __restrict__ out)
{
    int row = blockIdx.x, tid = threadIdx.x;
    const TIN* xr = x + (size_t)row * C_;
    float v0 = ldf(xr[tid]), v1 = ldf(xr[tid+256]), v2 = ldf(xr[tid+512]);
    float s = v0+v1+v2, q = v0*v0+v1*v1+v2*v2;
    #pragma unroll
    for (int off=32; off; off>>=1){ s += __shfl_xor(s,off); q += __shfl_xor(q,off); }
    __shared__ float ss[4], qq[4], mshare[2];
    int lane = tid & 63, wv = tid >> 6;
    if (!lane){ ss[wv] = s; qq[wv] = q; }
    __syncthreads();
    if (!tid){
        float S2 = ss[0]+ss[1]+ss[2]+ss[3];
        float Q2 = qq[0]+qq[1]+qq[2]+qq[3];
        float mean = S2 * (1.f/C_);
        float var  = Q2 * (1.f/C_) - mean*mean;
        mshare[0] = mean; mshare[1] = rsqrtf(var + 1e-6f);
    }
    __syncthreads();
    float mean = mshare[0], inv = mshare[1];
    unsigned short* orow = out + (size_t)row * C_;
    orow[tid]     = f2bf((v0-mean)*inv*g[tid]     + b[tid]);
    orow[tid+256] = f2bf((v1-mean)*inv*g[tid+256] + b[tid+256]);
    orow[tid+512] = f2bf((v2-mean)*inv*g[tid+512] + b[tid+512]);
}

// ---------------- RoPE tables ----------------
__global__ __launch_bounds__(256) void rope_tables_k(float* __restrict__ cosT,
                                                     float* __restrict__ sinT)
{
    int idx = blockIdx.x * 256 + threadIdx.x;
    if (idx >= S_*32) return;
    int s = idx >> 5, i = idx & 31;
    int hh = s / WW_, ww = s % WW_;
    int m = i & 15;
    float coord = (i < 16) ? (float)hh : (float)ww;
    float freq = powf(10000.0f, -(float)m / 16.0f);
    float a = coord * freq;
    float c = cosf(a), sn = sinf(a);
    cosT[s*64 + 2*i]   = c;  cosT[s*64 + 2*i+1] = c;
    sinT[s*64 + 2*i]   = sn; sinT[s*64 + 2*i+1] = sn;
}

// ---------------- RoPE apply (q scaled by 0.125) ----------------
__global__ __launch_bounds__(256) void rope_apply_k(unsigned short* __restrict__ q,
                                                    unsigned short* __restrict__ k,
                                                    const float* __restrict__ cosT,
                                                    const float* __restrict__ sinT)
{
    int idx = blockIdx.x * 256 + threadIdx.x;
    if (idx >= S_*NH_*32) return;
    int s = idx / (NH_*32);
    int p = idx % (NH_*32);
    int h = p >> 5, i = p & 31;
    size_t base = (size_t)s*C_ + h*HD_ + 2*i;
    float c = cosT[s*64 + 2*i], sn = sinT[s*64 + 2*i];
    float x0 = bf2f(q[base]), x1 = bf2f(q[base+1]);
    q[base]   = f2bf((x0*c - x1*sn) * 0.125f);
    q[base+1] = f2bf((x1*c + x0*sn) * 0.125f);
    x0 = bf2f(k[base]); x1 = bf2f(k[base+1]);
    k[base]   = f2bf(x0*c - x1*sn);
    k[base+1] = f2bf(x1*c + x0*sn);
}

// ---------------- Weight transpose: f32 W(K,N) -> bf16 WT(N,K) ----------------
__global__ __launch_bounds__(256) void transpose_w(const float* __restrict__ W,
                                                   unsigned short* __restrict__ WT,
                                                   int K, int N)
{
    __shared__ float t[32][33];
    int tx = threadIdx.x, ty = threadIdx.y;
    int n0 = blockIdx.x * 32, k0 = blockIdx.y * 32;
    #pragma unroll
    for (int i = 0; i < 4; i++)
        t[ty + i*8][tx] = W[(size_t)(k0 + ty + i*8)*N + n0 + tx];
    __syncthreads();
    #pragma unroll
    for (int i = 0; i < 4; i++)
        WT[(size_t)(n0 + ty + i*8)*K + k0 + tx] = f2bf(t[tx][ty + i*8]);
}

// ---------------- MFMA GEMM: bf16 A(M,K) @ bf16 BT(N,K)^T + bias ----------------
// EPI 0: bf16 out = acc+bias
// EPI 1: bf16 out = gelu(acc+bias)
// EPI 2: f32  out = (acc+bias)*scale + addend
// EPI 3: bf16 out = acc+bias, transposed to out[n*S_ + m]
// EPI 4: fused QK: bias=bq, scale=bk(second bias); out row pitch 768, k half at +S_*768
template<int EPI>
__global__ __launch_bounds__(256) void gemm_mfma(const unsigned short* __restrict__ A,
                                                 const unsigned short* __restrict__ BT,
                                                 const float* __restrict__ bias,
                                                 const float* __restrict__ scale,
                                                 const float* __restrict__ addend,
                                                 void* __restrict__ outp,
                                                 int M, int N, int K)
{
    __shared__ __align__(16) unsigned short As[8][128][8];
    __shared__ __align__(16) unsigned short Bs[8][128][8];
    int tid = threadIdx.x;
    int w = tid >> 6, lane = tid & 63, lq = lane & 15, lk = lane >> 4;
    int wr = w >> 1, wc = w & 1;
    int bm = blockIdx.y * 128, bn = blockIdx.x * 128;

    f32x4 acc[4][4];
    #pragma unroll
    for (int i = 0; i < 4; i++)
        #pragma unroll
        for (int j = 0; j < 4; j++) acc[i][j] = 0;

    for (int kt = 0; kt < K; kt += 64) {
        #pragma unroll
        for (int u = 0; u < 4; u++) {
            int t = w*4 + u;
            int c = t*64 + lane;
            int kg = c >> 7, row = c & 127;
            int ra = bm + row; if (ra >= M) ra = M - 1;
            gload16(A + (size_t)ra*K + kt + kg*8, ((const unsigned short*)As) + t*512);
            gload16(BT + (size_t)(bn + row)*K + kt + kg*8, ((const unsigned short*)Bs) + t*512);
        }
        __syncthreads();
        #pragma unroll
        for (int kk = 0; kk < 2; kk++) {
            bf16x8 af[4], bfr[4];
            #pragma unroll
            for (int mi = 0; mi < 4; mi++)
                af[mi] = *(const bf16x8*)&As[kk*4 + lk][wr*64 + mi*16 + lq][0];
            #pragma unroll
            for (int ni = 0; ni < 4; ni++)
                bfr[ni] = *(const bf16x8*)&Bs[kk*4 + lk][wc*64 + ni*16 + lq][0];
            #pragma unroll
            for (int mi = 0; mi < 4; mi++)
                #pragma unroll
                for (int ni = 0; ni < 4; ni++)
                    acc[mi][ni] = __builtin_amdgcn_mfma_f32_16x16x32_bf16(af[mi], bfr[ni], acc[mi][ni], 0, 0, 0);
        }
        __syncthreads();
    }

    #pragma unroll
    for (int mi = 0; mi < 4; mi++) {
        #pragma unroll
        for (int ni = 0; ni < 4; ni++) {
            #pragma unroll
            for (int r = 0; r < 4; r++) {
                int m = bm + wr*64 + mi*16 + lk*4 + r;
                int n = bn + wc*64 + ni*16 + lq;
                if (m < M) {
                    if (EPI == 4) {
                        float bv = (n < 768) ? bias[n] : scale[n - 768];
                        float v = acc[mi][ni][r] + bv;
                        size_t o = (size_t)m*768 + ((n < 768) ? (size_t)n : ((size_t)S_*768 + n - 768));
                        ((unsigned short*)outp)[o] = f2bf(v);
                    } else {
                        float v = acc[mi][ni][r] + bias[n];
                        if (EPI == 0) {
                            ((unsigned short*)outp)[(size_t)m*N + n] = f2bf(v);
                        } else if (EPI == 1) {
                            v = 0.5f * v * (1.f + erff(v * 0.70710678f));
                            ((unsigned short*)outp)[(size_t)m*N + n] = f2bf(v);
                        } else if (EPI == 2) {
                            size_t o = (size_t)m*N + n;
                            ((float*)outp)[o] = v*scale[n] + addend[o];
                        } else {
                            ((unsigned short*)outp)[(size_t)n*S_ + m] = f2bf(v);
                        }
                    }
                }
            }
        }
    }
}

// ---------------- MFMA flash attention v2 ----------------
// Swapped QK^T (P^T lane-local per q), permuted-k PV with P entirely in registers.
// Q,K packed bf16 [s][C] (Q pre-scaled), Vt bf16 [C][S], O packed bf16 [s][C].
__global__ __launch_bounds__(256) void attn_mfma2(const unsigned short* __restrict__ Q,
                                                  const unsigned short* __restrict__ Kb,
                                                  const unsigned short* __restrict__ Vt,
                                                  unsigned short* __restrict__ O)
{
    __shared__ __align__(16) unsigned short Ks[8][64][8];   // [dg][kv][j]   8KB
    __shared__ __align__(16) unsigned short Vs[8][64][8];   // [kvg][d][j]   8KB
    int tid = threadIdx.x;
    int w = tid >> 6, lane = tid & 63, lq = lane & 15, lk = lane >> 4;
    int h = blockIdx.y;
    int q0 = blockIdx.x * 128 + w * 32;      // this wave: 32 q rows (2 frags)

    // Q B-frags hoisted: qf[qi][ks] : B[k=d][col=q], lane holds Q[q0+qi*16+lq][ks*32+lk*8+j]
    bf16x8 qf[2][2];
    #pragma unroll
    for (int qi = 0; qi < 2; qi++) {
        int qr = q0 + qi*16 + lq; if (qr >= S_) qr = S_ - 1;
        #pragma unroll
        for (int ks = 0; ks < 2; ks++)
            qf[qi][ks] = *(const bf16x8*)(Q + (size_t)qr*C_ + h*64 + ks*32 + lk*8);
    }

    f32x4 oacc[2][4];       // [qi][df]: d = df*16 + lk*4 + r, q = q0+qi*16+lq
    #pragma unroll
    for (int qi = 0; qi < 2; qi++)
        #pragma unroll
        for (int df = 0; df < 4; df++) oacc[qi][df] = 0;
    float m_[2] = {-INFINITY, -INFINITY};
    float l_[2] = {0.f, 0.f};

    for (int t = 0; t < S_/64; t++) {
        int kv0 = t * 64;
        #pragma unroll
        for (int u = 0; u < 4; u++) {
            int tt = w*4 + u;
            if (tt < 8)
                gload16(Kb + (size_t)(kv0 + lane)*C_ + h*64 + tt*8,
                        ((const unsigned short*)Ks) + tt*512);
            else
                gload16(Vt + (size_t)(h*64 + lane)*S_ + kv0 + (tt-8)*8,
                        ((const unsigned short*)Vs) + (tt-8)*512);
        }
        __syncthreads();

        // P^T = K Q : s[qi][nf][r] = P[kv=nf*16+lk*4+r][q=lq]
        f32x4 s[2][4];
        #pragma unroll
        for (int qi = 0; qi < 2; qi++)
            #pragma unroll
            for (int nf = 0; nf < 4; nf++) s[qi][nf] = 0;
        #pragma unroll
        for (int ks = 0; ks < 2; ks++) {
            #pragma unroll
            for (int nf = 0; nf < 4; nf++) {
                bf16x8 kf = *(const bf16x8*)&Ks[ks*4 + lk][nf*16 + lq][0];
                #pragma unroll
                for (int qi = 0; qi < 2; qi++)
                    s[qi][nf] = __builtin_amdgcn_mfma_f32_16x16x32_bf16(kf, qf[qi][ks], s[qi][nf], 0, 0, 0);
            }
        }

        // online softmax (per lane: one q per qi, 16 kv in regs; cross-lk via 2 shfl)
        unsigned int pk[2][8];
        #pragma unroll
        for (int qi = 0; qi < 2; qi++) {
            float tm = -INFINITY;
            #pragma unroll
            for (int nf = 0; nf < 4; nf++)
                #pragma unroll
                for (int r = 0; r < 4; r++) tm = fmaxf(tm, s[qi][nf][r]);
            tm = fmaxf(tm, __shfl_xor(tm, 16));
            tm = fmaxf(tm, __shfl_xor(tm, 32));
            float mn = fmaxf(m_[qi], tm);
            float corr = __expf(m_[qi] - mn);
            m_[qi] = mn;
            float ps = 0.f;
            #pragma unroll
            for (int nf = 0; nf < 4; nf++)
                #pragma unroll
                for (int r = 0; r < 4; r++) {
                    float p = __expf(s[qi][nf][r] - mn);
                    s[qi][nf][r] = p; ps += p;
                }
            ps += __shfl_xor(ps, 16);
            ps += __shfl_xor(ps, 32);
            l_[qi] = l_[qi]*corr + ps;
            #pragma unroll
            for (int df = 0; df < 4; df++)
                #pragma unroll
                for (int r = 0; r < 4; r++) oacc[qi][df][r] *= corr;
            #pragma unroll
            for (int nf = 0; nf < 4; nf++) {
                pk[qi][nf*2+0] = cvtpk(s[qi][nf][0], s[qi][nf][1]);
                pk[qi][nf*2+1] = cvtpk(s[qi][nf][2], s[qi][nf][3]);
            }
        }

        // O^T += V P : permuted-k 16x16x32; A=V (2x b64 from Vs), B=P (lane's own pk words)
        #pragma unroll
        for (int ks = 0; ks < 2; ks++) {
            #pragma unroll
            for (int df = 0; df < 4; df++) {
                int d = df*16 + lq;
                union { bf16x8 v; unsigned long long dd[2]; } va;
                va.dd[0] = *(const unsigned long long*)&Vs[4*ks + (lk>>1)][d][(lk&1)*4];
                va.dd[1] = *(const unsigned long long*)&Vs[4*ks + 2 + (lk>>1)][d][(lk&1)*4];
                #pragma unroll
                for (int qi = 0; qi < 2; qi++) {
                    union { bf16x8 v; unsigned int u[4]; } pb;
                    pb.u[0] = pk[qi][4*ks+0]; pb.u[1] = pk[qi][4*ks+1];
                    pb.u[2] = pk[qi][4*ks+2]; pb.u[3] = pk[qi][4*ks+3];
                    oacc[qi][df] = __builtin_amdgcn_mfma_f32_16x16x32_bf16(va.v, pb.v, oacc[qi][df], 0, 0, 0);
                }
            }
        }
        __syncthreads();
    }

    #pragma unroll
    for (int qi = 0; qi < 2; qi++) {
        int q = q0 + qi*16 + lq;
        if (q < S_) {
            float rl = 1.f / l_[qi];
            #pragma unroll
            for (int df = 0; df < 4; df++) {
                ushort4 pv;
                pv.x = f2bf(oacc[qi][df][0] * rl);
                pv.y = f2bf(oacc[qi][df][1] * rl);
                pv.z = f2bf(oacc[qi][df][2] * rl);
                pv.w = f2bf(oacc[qi][df][3] * rl);
                *(ushort4*)(O + (size_t)q*C_ + h*64 + df*16 + lk*4) = pv;
            }
        }
    }
}

extern "C" void kernel_launch(void* const* d_in, const int* in_sizes, int n_in,
                              void* d_out, int out_size, void* d_ws, size_t ws_size,
                              hipStream_t stream)
{
    const float* hidden = (const float*)d_in[0];
    const float* wq  = (const float*)d_in[1];
    const float* bq  = (const float*)d_in[2];
    const float* wk  = (const float*)d_in[3];
    const float* bk  = (const float*)d_in[4];
    const float* wv  = (const float*)d_in[5];
    const float* bv  = (const float*)d_in[6];
    const float* wo  = (const float*)d_in[7];
    const float* bo  = (const float*)d_in[8];
    const float* g1  = (const float*)d_in[9];
    const float* b1  = (const float*)d_in[10];
    const float* g2  = (const float*)d_in[11];
    const float* b2  = (const float*)d_in[12];
    const float* wf1 = (const float*)d_in[13];
    const float* bf1 = (const float*)d_in[14];
    const float* wf2 = (const float*)d_in[15];
    const float* bf2_ = (const float*)d_in[16];
    const float* ls1 = (const float*)d_in[17];
    const float* ls2 = (const float*)d_in[18];

    char* ws = (char*)d_ws;
    size_t off = 0;
    auto alloc = [&](size_t bytes) { char* p = ws + off; off += (bytes + 255) & ~(size_t)255; return p; };

    float* res1          = (float*)alloc((size_t)S_*C_*4);
    float* cosT          = (float*)alloc((size_t)S_*64*4);
    float* sinT          = (float*)alloc((size_t)S_*64*4);
    unsigned short* lnb  = (unsigned short*)alloc((size_t)S_*C_*2);
    unsigned short* qb   = (unsigned short*)alloc((size_t)S_*C_*2);   // qb,kb contiguous (fused QK out)
    unsigned short* kb   = (unsigned short*)alloc((size_t)S_*C_*2);
    unsigned short* vtb  = (unsigned short*)alloc((size_t)S_*C_*2);   // V^T [C_][S_]
    unsigned short* ob   = (unsigned short*)alloc((size_t)S_*C_*2);
    unsigned short* fc1b = qb;   // alias qb..ob (4*S*C*2 == S*FF*2), dead by fc1
    unsigned short* wqT  = (unsigned short*)alloc((size_t)C_*C_*2);   // wqT,wkT contiguous
    unsigned short* wkT  = (unsigned short*)alloc((size_t)C_*C_*2);
    unsigned short* wvT  = (unsigned short*)alloc((size_t)C_*C_*2);
    unsigned short* woT  = (unsigned short*)alloc((size_t)C_*C_*2);
    unsigned short* wf1T = (unsigned short*)alloc((size_t)C_*FF_*2);
    unsigned short* wf2T = (unsigned short*)alloc((size_t)C_*FF_*2);
    float* outb = (float*)d_out;

    hipLaunchKernelGGL(transpose_w, dim3(C_/32, C_/32), dim3(32,8), 0, stream, wq,  wqT,  C_, C_);
    hipLaunchKernelGGL(transpose_w, dim3(C_/32, C_/32), dim3(32,8), 0, stream, wk,  wkT,  C_, C_);
    hipLaunchKernelGGL(transpose_w, dim3(C_/32, C_/32), dim3(32,8), 0, stream, wv,  wvT,  C_, C_);
    hipLaunchKernelGGL(transpose_w, dim3(C_/32, C_/32), dim3(32,8), 0, stream, wo,  woT,  C_, C_);
    hipLaunchKernelGGL(transpose_w, dim3(FF_/32, C_/32), dim3(32,8), 0, stream, wf1, wf1T, C_, FF_);
    hipLaunchKernelGGL(transpose_w, dim3(C_/32, FF_/32), dim3(32,8), 0, stream, wf2, wf2T, FF_, C_);
    hipLaunchKernelGGL(ln_k<float>, dim3(S_), dim3(256), 0, stream, hidden, g1, b1, lnb);
    hipLaunchKernelGGL(rope_tables_k, dim3((S_*32 + 255)/256), dim3(256), 0, stream, cosT, sinT);
    // fused Q+K projection (wqT|wkT contiguous, N=1536); out: qb rows then kb rows
    hipLaunchKernelGGL(gemm_mfma<4>, dim3(1536/128, 41), dim3(256), 0, stream,
                       lnb, wqT, bq, bk, (const float*)nullptr, (void*)qb, S_, 1536, C_);
    hipLaunchKernelGGL(gemm_mfma<3>, dim3(C_/128, 41), dim3(256), 0, stream,
                       lnb, wvT, bv, (const float*)nullptr, (const float*)nullptr, (void*)vtb, S_, C_, C_);
    hipLaunchKernelGGL(rope_apply_k, dim3((S_*NH_*32 + 255)/256), dim3(256), 0, stream,
                       qb, kb, cosT, sinT);
    hipLaunchKernelGGL(attn_mfma2, dim3((S_ + 127)/128, NH_), dim3(256), 0, stream, qb, kb, vtb, ob);
    hipLaunchKernelGGL(gemm_mfma<2>, dim3(C_/128, 41), dim3(256), 0, stream,
                       ob, woT, bo, ls1, hidden, (void*)res1, S_, C_, C_);
    hipLaunchKernelGGL(ln_k<float>, dim3(S_), dim3(256), 0, stream, res1, g2, b2, lnb);
    hipLaunchKernelGGL(gemm_mfma<1>, dim3(FF_/128, 41), dim3(256), 0, stream,
                       lnb, wf1T, bf1, (const float*)nullptr, (const float*)nullptr, (void*)fc1b, S_, FF_, C_);
    hipLaunchKernelGGL(gemm_mfma<2>, dim3(C_/128, 41), dim3(256), 0, stream,
                       fc1b, wf2T, bf2_, ls2, res1, (void*)outb, S_, C_, FF_);
    (void)in_sizes; (void)n_in; (void)out_size; (void)ws_size;
}

// Round 6
// 477.821 us; speedup vs baseline: 42.5413x; 1.1637x over previous
//
#include <hip/hip_runtime.h>

#define S_  5184
#define C_  768
#define NH_ 12
#define HD_ 64
#define FF_ 3072
#define WW_ 72

typedef __attribute__((ext_vector_type(8))) short bf16x8;
typedef __attribute__((ext_vector_type(4))) float f32x4;

__device__ __forceinline__ float bf2f(unsigned short u){
    unsigned int i = ((unsigned int)u) << 16; float f; __builtin_memcpy(&f,&i,4); return f;
}
__device__ __forceinline__ unsigned short f2bf(float f){
    unsigned int i; __builtin_memcpy(&i,&f,4);
    unsigned int r = (i + 0x7fffu + ((i>>16)&1u)) >> 16;
    return (unsigned short)r;
}
__device__ __forceinline__ float ldf(float v){ return v; }
__device__ __forceinline__ float ldf(unsigned short v){ return bf2f(v); }

__device__ __forceinline__ void gload16(const void* g, const void* l) {
    __builtin_amdgcn_global_load_lds((const __attribute__((address_space(1))) void*)g,
                                     (__attribute__((address_space(3))) void*)l, 16, 0, 0);
}
__device__ __forceinline__ unsigned int cvtpk(float lo, float hi){
    unsigned int r;
    asm volatile("v_cvt_pk_bf16_f32 %0, %1, %2" : "=v"(r) : "v"(lo), "v"(hi));
    return r;
}

// ---------------- LayerNorm ----------------
template<typename TIN>
__global__ __launch_bounds__(256) void ln_k(const TIN* __restrict__ x,
                                            const float* __restrict__ g,
                                            const float* __restrict__ b,
                                            unsigned short* __restrict__ out)
{
    int row = blockIdx.x, tid = threadIdx.x;
    const TIN* xr = x + (size_t)row * C_;
    float v0 = ldf(xr[tid]), v1 = ldf(xr[tid+256]), v2 = ldf(xr[tid+512]);
    float s = v0+v1+v2, q = v0*v0+v1*v1+v2*v2;
    #pragma unroll
    for (int off=32; off; off>>=1){ s += __shfl_xor(s,off); q += __shfl_xor(q,off); }
    __shared__ float ss[4], qq[4], mshare[2];
    int lane = tid & 63, wv = tid >> 6;
    if (!lane){ ss[wv] = s; qq[wv] = q; }
    __syncthreads();
    if (!tid){
        float S2 = ss[0]+ss[1]+ss[2]+ss[3];
        float Q2 = qq[0]+qq[1]+qq[2]+qq[3];
        float mean = S2 * (1.f/C_);
        float var  = Q2 * (1.f/C_) - mean*mean;
        mshare[0] = mean; mshare[1] = rsqrtf(var + 1e-6f);
    }
    __syncthreads();
    float mean = mshare[0], inv = mshare[1];
    unsigned short* orow = out + (size_t)row * C_;
    orow[tid]     = f2bf((v0-mean)*inv*g[tid]     + b[tid]);
    orow[tid+256] = f2bf((v1-mean)*inv*g[tid+256] + b[tid+256]);
    orow[tid+512] = f2bf((v2-mean)*inv*g[tid+512] + b[tid+512]);
}

// ---------------- RoPE tables ----------------
__global__ __launch_bounds__(256) void rope_tables_k(float* __restrict__ cosT,
                                                     float* __restrict__ sinT)
{
    int idx = blockIdx.x * 256 + threadIdx.x;
    if (idx >= S_*32) return;
    int s = idx >> 5, i = idx & 31;
    int hh = s / WW_, ww = s % WW_;
    int m = i & 15;
    float coord = (i < 16) ? (float)hh : (float)ww;
    float freq = powf(10000.0f, -(float)m / 16.0f);
    float a = coord * freq;
    float c = cosf(a), sn = sinf(a);
    cosT[s*64 + 2*i]   = c;  cosT[s*64 + 2*i+1] = c;
    sinT[s*64 + 2*i]   = sn; sinT[s*64 + 2*i+1] = sn;
}

// ---------------- RoPE apply (q scaled by 0.125) ----------------
__global__ __launch_bounds__(256) void rope_apply_k(unsigned short* __restrict__ q,
                                                    unsigned short* __restrict__ k,
                                                    const float* __restrict__ cosT,
                                                    const float* __restrict__ sinT)
{
    int idx = blockIdx.x * 256 + threadIdx.x;
    if (idx >= S_*NH_*32) return;
    int s = idx / (NH_*32);
    int p = idx % (NH_*32);
    int h = p >> 5, i = p & 31;
    size_t base = (size_t)s*C_ + h*HD_ + 2*i;
    float c = cosT[s*64 + 2*i], sn = sinT[s*64 + 2*i];
    float x0 = bf2f(q[base]), x1 = bf2f(q[base+1]);
    q[base]   = f2bf((x0*c - x1*sn) * 0.125f);
    q[base+1] = f2bf((x1*c + x0*sn) * 0.125f);
    x0 = bf2f(k[base]); x1 = bf2f(k[base+1]);
    k[base]   = f2bf(x0*c - x1*sn);
    k[base+1] = f2bf(x1*c + x0*sn);
}

// ---------------- Weight transpose: f32 W(K,N) -> bf16 WT(N,K) ----------------
__global__ __launch_bounds__(256) void transpose_w(const float* __restrict__ W,
                                                   unsigned short* __restrict__ WT,
                                                   int K, int N)
{
    __shared__ float t[32][33];
    int tx = threadIdx.x, ty = threadIdx.y;
    int n0 = blockIdx.x * 32, k0 = blockIdx.y * 32;
    #pragma unroll
    for (int i = 0; i < 4; i++)
        t[ty + i*8][tx] = W[(size_t)(k0 + ty + i*8)*N + n0 + tx];
    __syncthreads();
    #pragma unroll
    for (int i = 0; i < 4; i++)
        WT[(size_t)(n0 + ty + i*8)*K + k0 + tx] = f2bf(t[tx][ty + i*8]);
}

// ---------------- MFMA GEMM, 2-phase double-buffered ----------------
// NWC: wave-columns; BN = 64*NWC (128 or 64). BM=128, BK=64.
// EPI 1: bf16 out0 = gelu(acc+bias)
// EPI 2: f32  out0 = (acc+bias)*scale + addend
// EPI 4: fused QKV (N=2304): n<768 q->out0[m*768+n] (+bias); n<1536 k->out0[S*768+m*768+n-768] (+biasB);
//        else vT->out2[(n-1536)*S+m] (+biasC), ushort4 packed.
template<int EPI, int NWC>
__global__ __launch_bounds__(256) void gemm_mfma(const unsigned short* __restrict__ A,
                                                 const unsigned short* __restrict__ BT,
                                                 const float* __restrict__ bias,
                                                 const float* __restrict__ biasB,
                                                 const float* __restrict__ biasC,
                                                 const float* __restrict__ scale,
                                                 const float* __restrict__ addend,
                                                 void* __restrict__ outp,
                                                 void* __restrict__ outp2,
                                                 int M, int N, int K)
{
    const int BN = 64*NWC;
    const int MI = (NWC == 2) ? 4 : 2;
    __shared__ __align__(16) unsigned short As[2][8192];
    __shared__ __align__(16) unsigned short Bs[2][4096*NWC];
    int tid = threadIdx.x;
    int w = tid >> 6, lane = tid & 63, lq = lane & 15, lk = lane >> 4;
    int wr = (NWC == 2) ? (w >> 1) : w;
    int wc = (NWC == 2) ? (w & 1) : 0;
    int bm = blockIdx.y * 128, bn = blockIdx.x * BN;

    f32x4 acc[MI][4];
    #pragma unroll
    for (int i = 0; i < MI; i++)
        #pragma unroll
        for (int j = 0; j < 4; j++) acc[i][j] = 0;

    auto STAGE = [&](int buf, int kt) {
        #pragma unroll
        for (int u = 0; u < 4; u++) {
            int t = w*4 + u;
            int c = t*64 + lane;
            int kg = c >> 7, row = c & 127;
            int ra = bm + row; if (ra >= M) ra = M - 1;
            gload16(A + (size_t)ra*K + kt*64 + kg*8, As[buf] + t*512);
        }
        #pragma unroll
        for (int u = 0; u < 2*NWC; u++) {
            int t = w*2*NWC + u;
            int c = t*64 + lane;
            int kg = (NWC == 2) ? (c >> 7) : (c >> 6);
            int row = (NWC == 2) ? (c & 127) : (c & 63);
            gload16(BT + (size_t)(bn + row)*K + kt*64 + kg*8, Bs[buf] + t*512);
        }
    };

    int nk = K / 64;
    STAGE(0, 0);
    int cur = 0;
    for (int kt = 0; kt < nk; kt++) {
        __syncthreads();                         // drains cur-tile loads (vmcnt0 before barrier)
        if (kt + 1 < nk) STAGE(cur ^ 1, kt + 1); // overlap next-tile staging with compute
        #pragma unroll
        for (int kk = 0; kk < 2; kk++) {
            bf16x8 af[MI], bfr[4];
            #pragma unroll
            for (int mi = 0; mi < MI; mi++)
                af[mi] = *(const bf16x8*)(As[cur] + (kk*4 + lk)*1024 + (wr*MI*16 + mi*16 + lq)*8);
            #pragma unroll
            for (int ni = 0; ni < 4; ni++)
                bfr[ni] = *(const bf16x8*)(Bs[cur] + (kk*4 + lk)*BN*8 + (wc*64 + ni*16 + lq)*8);
            #pragma unroll
            for (int mi = 0; mi < MI; mi++)
                #pragma unroll
                for (int ni = 0; ni < 4; ni++)
                    acc[mi][ni] = __builtin_amdgcn_mfma_f32_16x16x32_bf16(af[mi], bfr[ni], acc[mi][ni], 0, 0, 0);
        }
        cur ^= 1;
    }

    #pragma unroll
    for (int mi = 0; mi < MI; mi++) {
        #pragma unroll
        for (int ni = 0; ni < 4; ni++) {
            int n = bn + wc*64 + ni*16 + lq;
            int m0 = bm + wr*MI*16 + mi*16 + lk*4;
            if (EPI == 4) {
                if (n < 1536) {
                    const float* bb = (n < 768) ? bias : biasB;
                    int nn = (n < 768) ? n : (n - 768);
                    size_t base = (n < 768) ? 0 : ((size_t)S_ * 768);
                    #pragma unroll
                    for (int r = 0; r < 4; r++) {
                        int m = m0 + r;
                        if (m < M)
                            ((unsigned short*)outp)[base + (size_t)m*768 + nn] = f2bf(acc[mi][ni][r] + bb[nn]);
                    }
                } else {
                    if (m0 < M) {
                        float bv = biasC[n - 1536];
                        ushort4 pv;
                        pv.x = f2bf(acc[mi][ni][0] + bv);
                        pv.y = f2bf(acc[mi][ni][1] + bv);
                        pv.z = f2bf(acc[mi][ni][2] + bv);
                        pv.w = f2bf(acc[mi][ni][3] + bv);
                        *(ushort4*)((unsigned short*)outp2 + (size_t)(n - 1536)*S_ + m0) = pv;
                    }
                }
            } else {
                #pragma unroll
                for (int r = 0; r < 4; r++) {
                    int m = m0 + r;
                    if (m < M) {
                        float v = acc[mi][ni][r] + bias[n];
                        if (EPI == 1) {
                            v = 0.5f * v * (1.f + erff(v * 0.70710678f));
                            ((unsigned short*)outp)[(size_t)m*N + n] = f2bf(v);
                        } else {
                            size_t o = (size_t)m*N + n;
                            ((float*)outp)[o] = v*scale[n] + addend[o];
                        }
                    }
                }
            }
        }
    }
}

// ---------------- MFMA flash attention, 2-phase double-buffered ----------------
__global__ __launch_bounds__(256) void attn_mfma2(const unsigned short* __restrict__ Q,
                                                  const unsigned short* __restrict__ Kb,
                                                  const unsigned short* __restrict__ Vt,
                                                  unsigned short* __restrict__ O)
{
    __shared__ __align__(16) unsigned short Ks[2][4096];   // [dg][kv][j]
    __shared__ __align__(16) unsigned short Vs[2][4096];   // [kvg][d][j]
    int tid = threadIdx.x;
    int w = tid >> 6, lane = tid & 63, lq = lane & 15, lk = lane >> 4;
    int h = blockIdx.y;
    int q0 = blockIdx.x * 128 + w * 32;

    bf16x8 qf[2][2];
    #pragma unroll
    for (int qi = 0; qi < 2; qi++) {
        int qr = q0 + qi*16 + lq; if (qr >= S_) qr = S_ - 1;
        #pragma unroll
        for (int ks = 0; ks < 2; ks++)
            qf[qi][ks] = *(const bf16x8*)(Q + (size_t)qr*C_ + h*64 + ks*32 + lk*8);
    }

    f32x4 oacc[2][4];
    #pragma unroll
    for (int qi = 0; qi < 2; qi++)
        #pragma unroll
        for (int df = 0; df < 4; df++) oacc[qi][df] = 0;
    float m_[2] = {-INFINITY, -INFINITY};
    float l_[2] = {0.f, 0.f};

    auto STAGE = [&](int buf, int t) {
        int kv0 = t * 64;
        #pragma unroll
        for (int u = 0; u < 4; u++) {
            int tt = w*4 + u;
            if (tt < 8)
                gload16(Kb + (size_t)(kv0 + lane)*C_ + h*64 + tt*8, Ks[buf] + tt*512);
            else
                gload16(Vt + (size_t)(h*64 + lane)*S_ + kv0 + (tt-8)*8, Vs[buf] + (tt-8)*512);
        }
    };

    const int NT = S_/64;
    STAGE(0, 0);
    int cur = 0;
    for (int t = 0; t < NT; t++) {
        __syncthreads();
        if (t + 1 < NT) STAGE(cur ^ 1, t + 1);

        // P^T = K Q
        f32x4 s[2][4];
        #pragma unroll
        for (int qi = 0; qi < 2; qi++)
            #pragma unroll
            for (int nf = 0; nf < 4; nf++) s[qi][nf] = 0;
        #pragma unroll
        for (int ks = 0; ks < 2; ks++) {
            #pragma unroll
            for (int nf = 0; nf < 4; nf++) {
                bf16x8 kf = *(const bf16x8*)(Ks[cur] + (ks*4 + lk)*512 + (nf*16 + lq)*8);
                #pragma unroll
                for (int qi = 0; qi < 2; qi++)
                    s[qi][nf] = __builtin_amdgcn_mfma_f32_16x16x32_bf16(kf, qf[qi][ks], s[qi][nf], 0, 0, 0);
            }
        }

        // online softmax (lane-local 16 kv per q; 2 shfl cross-lk)
        unsigned int pk[2][8];
        #pragma unroll
        for (int qi = 0; qi < 2; qi++) {
            float tm = -INFINITY;
            #pragma unroll
            for (int nf = 0; nf < 4; nf++)
                #pragma unroll
                for (int r = 0; r < 4; r++) tm = fmaxf(tm, s[qi][nf][r]);
            tm = fmaxf(tm, __shfl_xor(tm, 16));
            tm = fmaxf(tm, __shfl_xor(tm, 32));
            float mn = fmaxf(m_[qi], tm);
            float corr = __expf(m_[qi] - mn);
            m_[qi] = mn;
            float ps = 0.f;
            #pragma unroll
            for (int nf = 0; nf < 4; nf++)
                #pragma unroll
                for (int r = 0; r < 4; r++) {
                    float p = __expf(s[qi][nf][r] - mn);
                    s[qi][nf][r] = p; ps += p;
                }
            ps += __shfl_xor(ps, 16);
            ps += __shfl_xor(ps, 32);
            l_[qi] = l_[qi]*corr + ps;
            #pragma unroll
            for (int df = 0; df < 4; df++)
                #pragma unroll
                for (int r = 0; r < 4; r++) oacc[qi][df][r] *= corr;
            #pragma unroll
            for (int nf = 0; nf < 4; nf++) {
                pk[qi][nf*2+0] = cvtpk(s[qi][nf][0], s[qi][nf][1]);
                pk[qi][nf*2+1] = cvtpk(s[qi][nf][2], s[qi][nf][3]);
            }
        }

        // O^T += V P (permuted-k; B-frag = lane-local pk words)
        #pragma unroll
        for (int ks = 0; ks < 2; ks++) {
            #pragma unroll
            for (int df = 0; df < 4; df++) {
                int d = df*16 + lq;
                union { bf16x8 v; unsigned long long dd[2]; } va;
                va.dd[0] = *(const unsigned long long*)(Vs[cur] + (4*ks + (lk>>1))*512 + d*8 + (lk&1)*4);
                va.dd[1] = *(const unsigned long long*)(Vs[cur] + (4*ks + 2 + (lk>>1))*512 + d*8 + (lk&1)*4);
                #pragma unroll
                for (int qi = 0; qi < 2; qi++) {
                    union { bf16x8 v; unsigned int u[4]; } pb;
                    pb.u[0] = pk[qi][4*ks+0]; pb.u[1] = pk[qi][4*ks+1];
                    pb.u[2] = pk[qi][4*ks+2]; pb.u[3] = pk[qi][4*ks+3];
                    oacc[qi][df] = __builtin_amdgcn_mfma_f32_16x16x32_bf16(va.v, pb.v, oacc[qi][df], 0, 0, 0);
                }
            }
        }
        cur ^= 1;
    }

    #pragma unroll
    for (int qi = 0; qi < 2; qi++) {
        int q = q0 + qi*16 + lq;
        if (q < S_) {
            float rl = 1.f / l_[qi];
            #pragma unroll
            for (int df = 0; df < 4; df++) {
                ushort4 pv;
                pv.x = f2bf(oacc[qi][df][0] * rl);
                pv.y = f2bf(oacc[qi][df][1] * rl);
                pv.z = f2bf(oacc[qi][df][2] * rl);
                pv.w = f2bf(oacc[qi][df][3] * rl);
                *(ushort4*)(O + (size_t)q*C_ + h*64 + df*16 + lk*4) = pv;
            }
        }
    }
}

extern "C" void kernel_launch(void* const* d_in, const int* in_sizes, int n_in,
                              void* d_out, int out_size, void* d_ws, size_t ws_size,
                              hipStream_t stream)
{
    const float* hidden = (const float*)d_in[0];
    const float* wq  = (const float*)d_in[1];
    const float* bq  = (const float*)d_in[2];
    const float* wk  = (const float*)d_in[3];
    const float* bk  = (const float*)d_in[4];
    const float* wv  = (const float*)d_in[5];
    const float* bv  = (const float*)d_in[6];
    const float* wo  = (const float*)d_in[7];
    const float* bo  = (const float*)d_in[8];
    const float* g1  = (const float*)d_in[9];
    const float* b1  = (const float*)d_in[10];
    const float* g2  = (const float*)d_in[11];
    const float* b2  = (const float*)d_in[12];
    const float* wf1 = (const float*)d_in[13];
    const float* bf1 = (const float*)d_in[14];
    const float* wf2 = (const float*)d_in[15];
    const float* bf2_ = (const float*)d_in[16];
    const float* ls1 = (const float*)d_in[17];
    const float* ls2 = (const float*)d_in[18];

    char* ws = (char*)d_ws;
    size_t off = 0;
    auto alloc = [&](size_t bytes) { char* p = ws + off; off += (bytes + 255) & ~(size_t)255; return p; };

    float* res1          = (float*)alloc((size_t)S_*C_*4);
    float* cosT          = (float*)alloc((size_t)S_*64*4);
    float* sinT          = (float*)alloc((size_t)S_*64*4);
    unsigned short* lnb  = (unsigned short*)alloc((size_t)S_*C_*2);
    unsigned short* qb   = (unsigned short*)alloc((size_t)S_*C_*2);   // qb,kb contiguous (fused out)
    unsigned short* kb   = (unsigned short*)alloc((size_t)S_*C_*2);
    unsigned short* vtb  = (unsigned short*)alloc((size_t)S_*C_*2);   // V^T [C_][S_]
    unsigned short* ob   = (unsigned short*)alloc((size_t)S_*C_*2);
    unsigned short* fc1b = qb;   // alias qb..ob (4*S*C*2 == S*FF*2), dead by fc1
    unsigned short* wqT  = (unsigned short*)alloc((size_t)C_*C_*2);   // wqT,wkT,wvT contiguous
    unsigned short* wkT  = (unsigned short*)alloc((size_t)C_*C_*2);
    unsigned short* wvT  = (unsigned short*)alloc((size_t)C_*C_*2);
    unsigned short* woT  = (unsigned short*)alloc((size_t)C_*C_*2);
    unsigned short* wf1T = (unsigned short*)alloc((size_t)C_*FF_*2);
    unsigned short* wf2T = (unsigned short*)alloc((size_t)C_*FF_*2);
    float* outb = (float*)d_out;

    hipLaunchKernelGGL(transpose_w, dim3(C_/32, C_/32), dim3(32,8), 0, stream, wq,  wqT,  C_, C_);
    hipLaunchKernelGGL(transpose_w, dim3(C_/32, C_/32), dim3(32,8), 0, stream, wk,  wkT,  C_, C_);
    hipLaunchKernelGGL(transpose_w, dim3(C_/32, C_/32), dim3(32,8), 0, stream, wv,  wvT,  C_, C_);
    hipLaunchKernelGGL(transpose_w, dim3(C_/32, C_/32), dim3(32,8), 0, stream, wo,  woT,  C_, C_);
    hipLaunchKernelGGL(transpose_w, dim3(FF_/32, C_/32), dim3(32,8), 0, stream, wf1, wf1T, C_, FF_);
    hipLaunchKernelGGL(transpose_w, dim3(C_/32, FF_/32), dim3(32,8), 0, stream, wf2, wf2T, FF_, C_);
    hipLaunchKernelGGL(ln_k<float>, dim3(S_), dim3(256), 0, stream, hidden, g1, b1, lnb);
    hipLaunchKernelGGL(rope_tables_k, dim3((S_*32 + 255)/256), dim3(256), 0, stream, cosT, sinT);
    // fused QKV projection: N=2304 over wqT|wkT|wvT
    hipLaunchKernelGGL((gemm_mfma<4,2>), dim3(2304/128, 41), dim3(256), 0, stream,
                       lnb, wqT, bq, bk, bv, (const float*)nullptr, (const float*)nullptr,
                       (void*)qb, (void*)vtb, S_, 2304, C_);
    hipLaunchKernelGGL(rope_apply_k, dim3((S_*NH_*32 + 255)/256), dim3(256), 0, stream,
                       qb, kb, cosT, sinT);
    hipLaunchKernelGGL(attn_mfma2, dim3((S_ + 127)/128, NH_), dim3(256), 0, stream, qb, kb, vtb, ob);
    // o-proj + ls1 + residual -> res1 (f32)
    hipLaunchKernelGGL((gemm_mfma<2,1>), dim3(C_/64, 41), dim3(256), 0, stream,
                       ob, woT, bo, (const float*)nullptr, (const float*)nullptr, ls1, hidden,
                       (void*)res1, (void*)nullptr, S_, C_, C_);
    hipLaunchKernelGGL(ln_k<float>, dim3(S_), dim3(256), 0, stream, res1, g2, b2, lnb);
    // fc1 + gelu
    hipLaunchKernelGGL((gemm_mfma<1,2>), dim3(FF_/128, 41), dim3(256), 0, stream,
                       lnb, wf1T, bf1, (const float*)nullptr, (const float*)nullptr,
                       (const float*)nullptr, (const float*)nullptr,
                       (void*)fc1b, (void*)nullptr, S_, FF_, C_);
    // fc2 + ls2 + residual -> d_out (f32)
    hipLaunchKernelGGL((gemm_mfma<2,1>), dim3(C_/64, 41), dim3(256), 0, stream,
                       fc1b, wf2T, bf2_, (const float*)nullptr, (const float*)nullptr, ls2, res1,
                       (void*)outb, (void*)nullptr, S_, C_, FF_);
    (void)in_sizes; (void)n_in; (void)out_size; (void)ws_size;
}